// Round 11
// baseline (213.610 us; speedup 1.0000x reference)
//
#include <hip/hip_runtime.h>
#include <hip/hip_bf16.h>

typedef unsigned short ushort_t;
typedef __attribute__((ext_vector_type(8))) short short8;
typedef __attribute__((ext_vector_type(4))) float f32x4;
typedef __attribute__((ext_vector_type(2))) unsigned int uint2v;

#define B_  2
#define S_  2048
#define D_  1024
#define H_  16
#define DK_ 64

#define NEG_BIG (-1e30f)
// 1/sqrt(DK) * log2(e): folded into q at qkv_proj epilogue; softmax in exp2 domain
#define SCALE2 0.18033688011112042f

__device__ __forceinline__ void async16(const void* g, void* l) {
  __builtin_amdgcn_global_load_lds((const __attribute__((address_space(1))) void*)g,
                                   (__attribute__((address_space(3))) void*)l, 16, 0, 0);
}
__device__ __forceinline__ ushort_t f2bf(float x) {
  __hip_bfloat16 h = __float2bfloat16(x);
  ushort_t u; __builtin_memcpy(&u, &h, 2); return u;
}
__device__ __forceinline__ unsigned int pack_bf2(float lo, float hi) {
  __hip_bfloat162 h2 = __float22bfloat162_rn(make_float2(lo, hi));
  unsigned int u; __builtin_memcpy(&u, &h2, 4); return u;
}

// ---------------------------------------------------------------------------
// prep: z<3 -> Q/K/V f32->bf16 convert; z in 3..6 -> weight transpose+convert
// ---------------------------------------------------------------------------
__global__ __launch_bounds__(256) void prep(const float* Q, const float* K, const float* V,
                                            const float* W0, const float* W1,
                                            const float* W2, const float* W3,
                                            ushort_t* qb, ushort_t* kb, ushort_t* vb,
                                            ushort_t* Wt) {
  __shared__ float tile[64][65];
  int z = blockIdx.z;
  if (z < 3) {
    const float* src = (z == 0) ? Q : (z == 1) ? K : V;
    ushort_t* dst = (z == 0) ? qb : (z == 1) ? kb : vb;
    size_t i = ((size_t)blockIdx.x * 256 + threadIdx.x) * 8;
    f32x4 a = *(const f32x4*)(src + i);
    f32x4 b = *(const f32x4*)(src + i + 4);
    short8 p;
    p[0] = (short)f2bf(a[0]); p[1] = (short)f2bf(a[1]);
    p[2] = (short)f2bf(a[2]); p[3] = (short)f2bf(a[3]);
    p[4] = (short)f2bf(b[0]); p[5] = (short)f2bf(b[1]);
    p[6] = (short)f2bf(b[2]); p[7] = (short)f2bf(b[3]);
    *(short8*)(dst + i) = p;
  } else {
    if (blockIdx.x >= 256) return;
    int zz = z - 3;
    const float* W = (zz == 0) ? W0 : (zz == 1) ? W1 : (zz == 2) ? W2 : W3;
    ushort_t* O = Wt + (size_t)zz * D_ * D_;
    int bx = blockIdx.x & 15, by = blockIdx.x >> 4;
    int tx = threadIdx.x & 63, ty = threadIdx.x >> 6;
    int r0 = by * 64, c0 = bx * 64;
    for (int i = 0; i < 16; i++) {
      int r = ty + i * 4;
      tile[r][tx] = W[(size_t)(r0 + r) * D_ + c0 + tx];
    }
    __syncthreads();
    for (int i = 0; i < 16; i++) {
      int r = ty + i * 4;
      O[(size_t)(c0 + r) * D_ + r0 + tx] = f2bf(tile[tx][r]);
    }
  }
}

// ---------------------------------------------------------------------------
// GEMM core v3: BK=32 (occupancy-friendly 12/16 KB LDS) + seg-swizzle:
// stage global seg (lane&3)^((lane>>3)&3), read koff=(quad^((l16>>1)&3))*8
// -> 2-way bank aliasing (free) instead of 8-way on b128 frag reads.
// NT=4: 128-col tile (2x2 waves of 64x64). NT=2: 64-col tile (waves 64x32).
// ---------------------------------------------------------------------------
template <int NT>
__device__ __forceinline__ void gemm_core_t(const ushort_t* A, const ushort_t* Bt,
                                            int bm, int bn, f32x4 acc[4][NT],
                                            ushort_t* As, ushort_t* Bs,
                                            int lane, int w, int wm, int wn) {
  int l16 = lane & 15, quad = lane >> 4;
  for (int mi = 0; mi < 4; mi++)
    for (int ni = 0; ni < NT; ni++) acc[mi][ni] = (f32x4){0.f, 0.f, 0.f, 0.f};
  int srow = lane >> 2;                              // 16 rows per issue
  int sseg = ((lane & 3) ^ ((lane >> 3) & 3)) * 8;   // swizzled global seg
  int koff = (quad ^ ((l16 >> 1) & 3)) * 8;          // read-side swizzle
  for (int k0 = 0; k0 < D_; k0 += 32) {
    __syncthreads();
    for (int j = 0; j < 2; j++) {       // A: 128 rows x 32 k
      int rb = w * 32 + j * 16;
      async16(A + (size_t)(bm + rb + srow) * D_ + k0 + sseg, As + rb * 32);
    }
    for (int j = 0; j < NT / 2; j++) {  // B: NT*32 rows x 32 k
      int rb = w * 16 * (NT / 2) + j * 16;
      async16(Bt + (size_t)(bn + rb + srow) * D_ + k0 + sseg, Bs + rb * 32);
    }
    __syncthreads();
    short8 af[4], bfv[NT];
    for (int mi = 0; mi < 4; mi++)
      af[mi] = *(const short8*)(As + (wm + mi * 16 + l16) * 32 + koff);
    for (int ni = 0; ni < NT; ni++)
      bfv[ni] = *(const short8*)(Bs + (wn + ni * 16 + l16) * 32 + koff);
    for (int mi = 0; mi < 4; mi++)
      for (int ni = 0; ni < NT; ni++)
        acc[mi][ni] = __builtin_amdgcn_mfma_f32_16x16x32_bf16(af[mi], bfv[ni], acc[mi][ni], 0, 0, 0);
  }
}

// Fused QKV projection: z=0 -> qh (pre-scaled by SCALE2), z=1 -> kh, z=2 -> vT.
// z=2 epilogue transposes 128x128 output tile via LDS (two 64-col passes) so
// vT [B,H,DK,S] stores are fully coalesced instead of 2B scatters.
__global__ __launch_bounds__(256) void qkv_proj(const ushort_t* qb, const ushort_t* kb,
                                                const ushort_t* vb, const ushort_t* Wt,
                                                ushort_t* qh, ushort_t* kh, ushort_t* vT) {
  __shared__ alignas(16) ushort_t Sh[8704];  // As(4096)+Bs(4096); reused 64x136 T
  ushort_t* As = Sh;
  ushort_t* Bs = Sh + 4096;
  int tid = threadIdx.x, lane = tid & 63, w = tid >> 6;
  int wm = (w & 1) * 64, wn = (w >> 1) * 64;
  int bm = blockIdx.y * 128, bn = blockIdx.x * 128;
  int z = blockIdx.z;
  const ushort_t* A = (z == 0) ? qb : (z == 1) ? kb : vb;
  const ushort_t* Bt = Wt + (size_t)z * D_ * D_;
  f32x4 acc[4][4];
  gemm_core_t<4>(A, Bt, bm, bn, acc, As, Bs, lane, w, wm, wn);
  int l16 = lane & 15, quad = lane >> 4;
  if (z == 2) {
    int b = bm >> 11, s0 = bm & (S_ - 1);
    for (int p = 0; p < 2; p++) {
      __syncthreads();
      if ((w >> 1) == p) {  // waves owning cols p*64..p*64+63 write T[col][s]
        for (int mi = 0; mi < 4; mi++)
          for (int ni = 0; ni < 4; ni++)
            for (int r = 0; r < 4; r++)
              Sh[(ni * 16 + l16) * 136 + wm + mi * 16 + quad * 4 + r] = f2bf(acc[mi][ni][r]);
      }
      __syncthreads();
      for (int c = tid; c < 1024; c += 256) {  // 64 rows x 16 segs of 16B
        int row = c >> 4, seg = c & 15;
        int colg = bn + p * 64 + row;
        int h = colg >> 6, dk = colg & 63;
        short8 t = *(const short8*)(Sh + row * 136 + seg * 8);
        *(short8*)(vT + ((size_t)(b * H_ + h) * DK_ + dk) * S_ + s0 + seg * 8) = t;
      }
    }
  } else {
    float qscale = (z == 0) ? SCALE2 : 1.0f;
    ushort_t* dst = (z == 0) ? qh : kh;
    for (int mi = 0; mi < 4; mi++)
      for (int ni = 0; ni < 4; ni++)
        for (int r = 0; r < 4; r++) {
          int row = bm + wm + mi * 16 + quad * 4 + r;  // = b*S + s
          int col = bn + wn + ni * 16 + l16;           // = h*64 + dk
          int b = row >> 11, s = row & (S_ - 1);
          int h = col >> 6, dk = col & 63;
          dst[((size_t)(b * H_ + h) * S_ + s) * DK_ + dk] = f2bf(acc[mi][ni][r] * qscale);
        }
  }
}

// Output projection + bias: C[B*S, D] (f32) = A(bf16) @ WoT^T + bo(f32)
// NT=4 128x128 tile (round-7 config: best measured for this kernel).
__global__ __launch_bounds__(256) void out_proj(const ushort_t* A, const ushort_t* Wt,
                                                const float* bias, float* C) {
  __shared__ alignas(16) ushort_t As[128 * 32];
  __shared__ alignas(16) ushort_t Bs[128 * 32];
  int tid = threadIdx.x, lane = tid & 63, w = tid >> 6;
  int wm = (w & 1) * 64, wn = (w >> 1) * 64;
  int bm = blockIdx.y * 128, bn = blockIdx.x * 128;
  f32x4 acc[4][4];
  gemm_core_t<4>(A, Wt, bm, bn, acc, As, Bs, lane, w, wm, wn);
  int l16 = lane & 15, quad = lane >> 4;
  for (int ni = 0; ni < 4; ni++) {
    int col = bn + wn + ni * 16 + l16;
    float bv = bias[col];
    for (int mi = 0; mi < 4; mi++)
      for (int r = 0; r < 4; r++) {
        int row = bm + wm + mi * 16 + quad * 4 + r;
        C[(size_t)row * D_ + col] = acc[mi][ni][r] + bv;
      }
  }
}

// ---------------------------------------------------------------------------
// Flash attention v6: S^T + fixed-scale softmax; ONE 64-row q-tile per block,
// grid 1024 (3 blocks/CU resident = 12 waves/CU), LPT order (longest j first).
// qh (pre-scaled), kh: [B,H,S,DK]; vT: [B,H,DK,S]; out: [B,S,D] bf16.
// ---------------------------------------------------------------------------
__global__ __launch_bounds__(256) void flash_attn(const ushort_t* qh, const ushort_t* kh,
                                                  const ushort_t* vT, ushort_t* outO) {
  __shared__ alignas(16) ushort_t Ks[2][64 * 64];   // [t][dk], seg^=row&7
  __shared__ alignas(16) ushort_t Vs[2][64 * 64];   // [dk][t], seg^=row&7
  __shared__ alignas(16) ushort_t Ps[4][16 * 72];   // per-wave P [m][t], stride 72
  int tid = threadIdx.x, lane = tid & 63, w = tid >> 6;
  int l16 = lane & 15, quad = lane >> 4;
  int j = 31 - (int)(blockIdx.x >> 5);  // LPT: longest q-tiles first
  int bh = blockIdx.x & 31;
  int b = bh >> 4, h = bh & 15;
  int qs = j * 64;
  int nt = j + 1;
  const ushort_t* qb = qh + (size_t)bh * S_ * DK_;
  const ushort_t* kb = kh + (size_t)bh * S_ * DK_;
  const ushort_t* vb = vT + (size_t)bh * DK_ * S_;
  ushort_t* ps = Ps[w];
  int srow = lane >> 3;
  int lseg8 = ((lane & 7) ^ srow) * 8;
  int swz = l16 & 7;
  int wrow = w * 16;

  short8 qf[2];  // Q B-operand: n = m = l16, k = dk = st*32 + quad*8 + jj
  {
    const ushort_t* qp = qb + (size_t)(qs + wrow + l16) * DK_;
    qf[0] = *(const short8*)(qp + quad * 8);
    qf[1] = *(const short8*)(qp + 32 + quad * 8);
  }
  float l_part = 0.f;  // per-lane partial sum of p over this lane's 16 t's
  f32x4 o[4];          // o^T frag: row = dk = f*16+quad*4+r, col = m = l16
  for (int f = 0; f < 4; f++) o[f] = (f32x4){0.f, 0.f, 0.f, 0.f};

  int buf = 0;
  for (int jj = 0; jj < 2; jj++) {  // prologue: tile 0 into buf 0
    int rb = w * 16 + jj * 8;
    async16(kb + (size_t)(rb + srow) * DK_ + lseg8, Ks[0] + rb * 64);
    async16(vb + (size_t)(rb + srow) * S_ + lseg8, Vs[0] + rb * 64);
  }
  for (int it = 0; it < nt; it++) {
    int t0 = it << 6;
    __syncthreads();  // drains tile `it` DMA; collective
    if (it + 1 < nt) {
      int t1 = t0 + 64, nb = buf ^ 1;
      for (int jj = 0; jj < 2; jj++) {
        int rb = w * 16 + jj * 8;
        async16(kb + (size_t)(t1 + rb + srow) * DK_ + lseg8, Ks[nb] + rb * 64);
        async16(vb + (size_t)(rb + srow) * S_ + t1 + lseg8, Vs[nb] + rb * 64);
      }
    }
    const ushort_t* Kb = Ks[buf];
    const ushort_t* Vb = Vs[buf];
    // S^T = K·Q^T: frag sf[f]: row = t = t0+f*16+quad*4+r, col = m = l16
    f32x4 sf[4];
    for (int f = 0; f < 4; f++) sf[f] = (f32x4){0.f, 0.f, 0.f, 0.f};
    for (int st = 0; st < 2; st++) {
      short8 kfr[4];
      for (int f = 0; f < 4; f++)
        kfr[f] = *(const short8*)(Kb + (f * 16 + l16) * 64 + (((st * 4 + quad) ^ swz) * 8));
      for (int f = 0; f < 4; f++)
        sf[f] = __builtin_amdgcn_mfma_f32_16x16x32_bf16(kfr[f], qf[st], sf[f], 0, 0, 0);
    }
    if (it == nt - 1) {  // diagonal tile: causal mask (t > s)
      int s = qs + wrow + l16;
      for (int f = 0; f < 4; f++) {
        int tb = t0 + f * 16 + quad * 4;
        for (int r = 0; r < 4; r++)
          if (tb + r > s) sf[f][r] = NEG_BIG;
      }
    }
    // fixed-scale softmax: p = exp2(s) (masked -> 0), accumulate partial l
    for (int f = 0; f < 4; f++)
      for (int r = 0; r < 4; r++) {
        float pv = exp2f(sf[f][r]);
        sf[f][r] = pv;
        l_part += pv;
      }
    // P pack: r-adjacent = t-adjacent -> b64 writes into [m][t] stride-72
    for (int f = 0; f < 4; f++) {
      uint2v pk;
      pk.x = pack_bf2(sf[f][0], sf[f][1]);
      pk.y = pack_bf2(sf[f][2], sf[f][3]);
      *(uint2v*)(ps + l16 * 72 + f * 16 + quad * 4) = pk;
    }
    asm volatile("s_waitcnt lgkmcnt(0)" ::: "memory");
    // PV: o^T += V^T(A) · P^T(B); B-frag: n = m = l16, k = t = st*32+quad*8+jj
    for (int st = 0; st < 2; st++) {
      short8 vfr[4];
      for (int f = 0; f < 4; f++)
        vfr[f] = *(const short8*)(Vb + (f * 16 + l16) * 64 + (((st * 4 + quad) ^ swz) * 8));
      short8 pf = *(const short8*)(ps + l16 * 72 + st * 32 + quad * 8);
      for (int f = 0; f < 4; f++)
        o[f] = __builtin_amdgcn_mfma_f32_16x16x32_bf16(vfr[f], pf, o[f], 0, 0, 0);
    }
    buf ^= 1;
  }
  // single end-of-tile l reduction across quads, then normalized store
  float l_r = l_part;
  l_r += __shfl_xor(l_r, 16, 64);
  l_r += __shfl_xor(l_r, 32, 64);
  float inv = 1.0f / l_r;
  int s = qs + wrow + l16;
  ushort_t* op = outO + (size_t)(b * S_ + s) * D_ + h * DK_;
  for (int f = 0; f < 4; f++) {
    uint2v pk;
    pk.x = pack_bf2(o[f][0] * inv, o[f][1] * inv);
    pk.y = pack_bf2(o[f][2] * inv, o[f][3] * inv);
    *(uint2v*)(op + f * 16 + quad * 4) = pk;
  }
}

// ---------------------------------------------------------------------------
extern "C" void kernel_launch(void* const* d_in, const int* in_sizes, int n_in,
                              void* d_out, int out_size, void* d_ws, size_t ws_size,
                              hipStream_t stream) {
  const float* Q  = (const float*)d_in[0];
  const float* K  = (const float*)d_in[1];
  const float* V  = (const float*)d_in[2];
  const float* Wq = (const float*)d_in[3];
  const float* Wk = (const float*)d_in[4];
  const float* Wv = (const float*)d_in[5];
  const float* Wo = (const float*)d_in[6];
  const float* bo = (const float*)d_in[7];
  ushort_t* ws = (ushort_t*)d_ws;
  ushort_t* Wt = ws;
  ushort_t* qb = ws + ((size_t)4 << 20);
  ushort_t* kb = ws + ((size_t)8 << 20);
  ushort_t* vb = ws + ((size_t)12 << 20);
  ushort_t* qh = ws + ((size_t)16 << 20);
  ushort_t* kh = ws + ((size_t)20 << 20);
  ushort_t* vT = ws + ((size_t)24 << 20);
  ushort_t* aO = qb;

  prep<<<dim3(2048, 1, 7), 256, 0, stream>>>(Q, K, V, Wq, Wk, Wv, Wo, qb, kb, vb, Wt);
  qkv_proj<<<dim3(8, 32, 3), 256, 0, stream>>>(qb, kb, vb, Wt, qh, kh, vT);
  flash_attn<<<1024, 256, 0, stream>>>(qh, kh, vT, aO);
  out_proj<<<dim3(8, 32, 1), 256, 0, stream>>>(aO, Wt + ((size_t)3 << 20), bo, (float*)d_out);
}

// Round 12
// 207.796 us; speedup vs baseline: 1.0280x; 1.0280x over previous
//
#include <hip/hip_runtime.h>
#include <hip/hip_bf16.h>

typedef unsigned short ushort_t;
typedef __attribute__((ext_vector_type(8))) short short8;
typedef __attribute__((ext_vector_type(4))) float f32x4;
typedef __attribute__((ext_vector_type(2))) unsigned int uint2v;

#define B_  2
#define S_  2048
#define D_  1024
#define H_  16
#define DK_ 64

#define NEG_BIG (-1e30f)
// 1/sqrt(DK) * log2(e): folded into q at qkv_proj epilogue; softmax in exp2 domain
#define SCALE2 0.18033688011112042f

__device__ __forceinline__ void async16(const void* g, void* l) {
  __builtin_amdgcn_global_load_lds((const __attribute__((address_space(1))) void*)g,
                                   (__attribute__((address_space(3))) void*)l, 16, 0, 0);
}
__device__ __forceinline__ ushort_t f2bf(float x) {
  __hip_bfloat16 h = __float2bfloat16(x);
  ushort_t u; __builtin_memcpy(&u, &h, 2); return u;
}
__device__ __forceinline__ unsigned int pack_bf2(float lo, float hi) {
  __hip_bfloat162 h2 = __float22bfloat162_rn(make_float2(lo, hi));
  unsigned int u; __builtin_memcpy(&u, &h2, 4); return u;
}

// ---------------------------------------------------------------------------
// prep (exact-sized 1D grid, no no-op blocks):
//   blk <  6144 : Q/K/V f32->bf16 convert (z = blk>>11, 2048 blocks each)
//   blk >= 6144 : weight transpose+convert (4 x 256 tile-blocks)
// ---------------------------------------------------------------------------
__global__ __launch_bounds__(256) void prep(const float* Q, const float* K, const float* V,
                                            const float* W0, const float* W1,
                                            const float* W2, const float* W3,
                                            ushort_t* qb, ushort_t* kb, ushort_t* vb,
                                            ushort_t* Wt) {
  __shared__ float tile[64][65];
  int blk = blockIdx.x;
  if (blk < 6144) {
    int z = blk >> 11, xi = blk & 2047;
    const float* src = (z == 0) ? Q : (z == 1) ? K : V;
    ushort_t* dst = (z == 0) ? qb : (z == 1) ? kb : vb;
    size_t i = ((size_t)xi * 256 + threadIdx.x) * 8;
    f32x4 a = *(const f32x4*)(src + i);
    f32x4 b = *(const f32x4*)(src + i + 4);
    short8 p;
    p[0] = (short)f2bf(a[0]); p[1] = (short)f2bf(a[1]);
    p[2] = (short)f2bf(a[2]); p[3] = (short)f2bf(a[3]);
    p[4] = (short)f2bf(b[0]); p[5] = (short)f2bf(b[1]);
    p[6] = (short)f2bf(b[2]); p[7] = (short)f2bf(b[3]);
    *(short8*)(dst + i) = p;
  } else {
    int wid = blk - 6144;
    int zz = wid >> 8, t = wid & 255;
    const float* W = (zz == 0) ? W0 : (zz == 1) ? W1 : (zz == 2) ? W2 : W3;
    ushort_t* O = Wt + (size_t)zz * D_ * D_;
    int bx = t & 15, by = t >> 4;
    int tx = threadIdx.x & 63, ty = threadIdx.x >> 6;
    int r0 = by * 64, c0 = bx * 64;
    for (int i = 0; i < 16; i++) {
      int r = ty + i * 4;
      tile[r][tx] = W[(size_t)(r0 + r) * D_ + c0 + tx];
    }
    __syncthreads();
    for (int i = 0; i < 16; i++) {
      int r = ty + i * 4;
      O[(size_t)(c0 + r) * D_ + r0 + tx] = f2bf(tile[tx][r]);
    }
  }
}

// ---------------------------------------------------------------------------
// GEMM core: BK=32 + seg-swizzle (stage global seg (lane&3)^((lane>>3)&3),
// read koff=(quad^((l16>>1)&3))*8 -> 2-way bank aliasing, free).
// NT=4: 128-col tile (2x2 waves of 64x64). NT=2: 64-col tile (waves 64x32).
// ---------------------------------------------------------------------------
template <int NT>
__device__ __forceinline__ void gemm_core_t(const ushort_t* A, const ushort_t* Bt,
                                            int bm, int bn, f32x4 acc[4][NT],
                                            ushort_t* As, ushort_t* Bs,
                                            int lane, int w, int wm, int wn) {
  int l16 = lane & 15, quad = lane >> 4;
  for (int mi = 0; mi < 4; mi++)
    for (int ni = 0; ni < NT; ni++) acc[mi][ni] = (f32x4){0.f, 0.f, 0.f, 0.f};
  int srow = lane >> 2;                              // 16 rows per issue
  int sseg = ((lane & 3) ^ ((lane >> 3) & 3)) * 8;   // swizzled global seg
  int koff = (quad ^ ((l16 >> 1) & 3)) * 8;          // read-side swizzle
  for (int k0 = 0; k0 < D_; k0 += 32) {
    __syncthreads();
    for (int j = 0; j < 2; j++) {       // A: 128 rows x 32 k
      int rb = w * 32 + j * 16;
      async16(A + (size_t)(bm + rb + srow) * D_ + k0 + sseg, As + rb * 32);
    }
    for (int j = 0; j < NT / 2; j++) {  // B: NT*32 rows x 32 k
      int rb = w * 16 * (NT / 2) + j * 16;
      async16(Bt + (size_t)(bn + rb + srow) * D_ + k0 + sseg, Bs + rb * 32);
    }
    __syncthreads();
    short8 af[4], bfv[NT];
    for (int mi = 0; mi < 4; mi++)
      af[mi] = *(const short8*)(As + (wm + mi * 16 + l16) * 32 + koff);
    for (int ni = 0; ni < NT; ni++)
      bfv[ni] = *(const short8*)(Bs + (wn + ni * 16 + l16) * 32 + koff);
    for (int mi = 0; mi < 4; mi++)
      for (int ni = 0; ni < NT; ni++)
        acc[mi][ni] = __builtin_amdgcn_mfma_f32_16x16x32_bf16(af[mi], bfv[ni], acc[mi][ni], 0, 0, 0);
  }
}

// Fused QKV projection: z=0 -> qh (pre-scaled by SCALE2), z=1 -> kh, z=2 -> vT.
// z=2 epilogue transposes 128x128 output tile via LDS (two 64-col passes) so
// vT [B,H,DK,S] stores are fully coalesced instead of 2B scatters.
__global__ __launch_bounds__(256) void qkv_proj(const ushort_t* qb, const ushort_t* kb,
                                                const ushort_t* vb, const ushort_t* Wt,
                                                ushort_t* qh, ushort_t* kh, ushort_t* vT) {
  __shared__ alignas(16) ushort_t Sh[8704];  // As(4096)+Bs(4096); reused 64x136 T
  ushort_t* As = Sh;
  ushort_t* Bs = Sh + 4096;
  int tid = threadIdx.x, lane = tid & 63, w = tid >> 6;
  int wm = (w & 1) * 64, wn = (w >> 1) * 64;
  int bm = blockIdx.y * 128, bn = blockIdx.x * 128;
  int z = blockIdx.z;
  const ushort_t* A = (z == 0) ? qb : (z == 1) ? kb : vb;
  const ushort_t* Bt = Wt + (size_t)z * D_ * D_;
  f32x4 acc[4][4];
  gemm_core_t<4>(A, Bt, bm, bn, acc, As, Bs, lane, w, wm, wn);
  int l16 = lane & 15, quad = lane >> 4;
  if (z == 2) {
    int b = bm >> 11, s0 = bm & (S_ - 1);
    for (int p = 0; p < 2; p++) {
      __syncthreads();
      if ((w >> 1) == p) {  // waves owning cols p*64..p*64+63 write T[col][s]
        for (int mi = 0; mi < 4; mi++)
          for (int ni = 0; ni < 4; ni++)
            for (int r = 0; r < 4; r++)
              Sh[(ni * 16 + l16) * 136 + wm + mi * 16 + quad * 4 + r] = f2bf(acc[mi][ni][r]);
      }
      __syncthreads();
      for (int c = tid; c < 1024; c += 256) {  // 64 rows x 16 segs of 16B
        int row = c >> 4, seg = c & 15;
        int colg = bn + p * 64 + row;
        int h = colg >> 6, dk = colg & 63;
        short8 t = *(const short8*)(Sh + row * 136 + seg * 8);
        *(short8*)(vT + ((size_t)(b * H_ + h) * DK_ + dk) * S_ + s0 + seg * 8) = t;
      }
    }
  } else {
    float qscale = (z == 0) ? SCALE2 : 1.0f;
    ushort_t* dst = (z == 0) ? qh : kh;
    for (int mi = 0; mi < 4; mi++)
      for (int ni = 0; ni < 4; ni++)
        for (int r = 0; r < 4; r++) {
          int row = bm + wm + mi * 16 + quad * 4 + r;  // = b*S + s
          int col = bn + wn + ni * 16 + l16;           // = h*64 + dk
          int b = row >> 11, s = row & (S_ - 1);
          int h = col >> 6, dk = col & 63;
          dst[((size_t)(b * H_ + h) * S_ + s) * DK_ + dk] = f2bf(acc[mi][ni][r] * qscale);
        }
  }
}

// Output projection + bias: C[B*S, D] (f32) = A(bf16) @ WoT^T + bo(f32)
// NT=2, BN=64, grid 512 (2 blocks/CU) — measured-best config (R9).
__global__ __launch_bounds__(256) void out_proj(const ushort_t* A, const ushort_t* Wt,
                                                const float* bias, float* C) {
  __shared__ alignas(16) ushort_t As[128 * 32];
  __shared__ alignas(16) ushort_t Bs[64 * 32];
  int tid = threadIdx.x, lane = tid & 63, w = tid >> 6;
  int wm = (w & 1) * 64, wn = (w >> 1) * 32;
  int bm = blockIdx.y * 128, bn = blockIdx.x * 64;
  f32x4 acc[4][2];
  gemm_core_t<2>(A, Wt, bm, bn, acc, As, Bs, lane, w, wm, wn);
  int l16 = lane & 15, quad = lane >> 4;
  for (int ni = 0; ni < 2; ni++) {
    int col = bn + wn + ni * 16 + l16;
    float bv = bias[col];
    for (int mi = 0; mi < 4; mi++)
      for (int r = 0; r < 4; r++) {
        int row = bm + wm + mi * 16 + quad * 4 + r;
        C[(size_t)row * D_ + col] = acc[mi][ni][r] + bv;
      }
  }
}

// ---------------------------------------------------------------------------
// Flash attention v7: as v6 but Ps is stride-64 XOR-swizzled (8 KB) -> total
// LDS 40960 B = 4 blocks/CU resident (grid 1024 fully co-resident).
// qh (pre-scaled), kh: [B,H,S,DK]; vT: [B,H,DK,S]; out: [B,S,D] bf16.
// ---------------------------------------------------------------------------
__global__ __launch_bounds__(256) void flash_attn(const ushort_t* qh, const ushort_t* kh,
                                                  const ushort_t* vT, ushort_t* outO) {
  __shared__ alignas(16) ushort_t Ks[2][64 * 64];   // [t][dk], seg^=row&7
  __shared__ alignas(16) ushort_t Vs[2][64 * 64];   // [dk][t], seg^=row&7
  __shared__ alignas(16) ushort_t Ps[4][16 * 64];   // per-wave P, col4 ^ (l16&7)<<1
  int tid = threadIdx.x, lane = tid & 63, w = tid >> 6;
  int l16 = lane & 15, quad = lane >> 4;
  int j = 31 - (int)(blockIdx.x >> 5);  // LPT: longest q-tiles first
  int bh = blockIdx.x & 31;
  int b = bh >> 4, h = bh & 15;
  int qs = j * 64;
  int nt = j + 1;
  const ushort_t* qb = qh + (size_t)bh * S_ * DK_;
  const ushort_t* kb = kh + (size_t)bh * S_ * DK_;
  const ushort_t* vb = vT + (size_t)bh * DK_ * S_;
  ushort_t* ps = Ps[w];
  int srow = lane >> 3;
  int lseg8 = ((lane & 7) ^ srow) * 8;
  int swz = l16 & 7;
  int pm = (l16 & 7) << 1;  // P col4 xor mask (even -> b64/b128 stay contiguous)
  int wrow = w * 16;

  short8 qf[2];  // Q B-operand: n = m = l16, k = dk = st*32 + quad*8 + jj
  {
    const ushort_t* qp = qb + (size_t)(qs + wrow + l16) * DK_;
    qf[0] = *(const short8*)(qp + quad * 8);
    qf[1] = *(const short8*)(qp + 32 + quad * 8);
  }
  float l_part = 0.f;  // per-lane partial sum of p over this lane's 16 t's
  f32x4 o[4];          // o^T frag: row = dk = f*16+quad*4+r, col = m = l16
  for (int f = 0; f < 4; f++) o[f] = (f32x4){0.f, 0.f, 0.f, 0.f};

  int buf = 0;
  for (int jj = 0; jj < 2; jj++) {  // prologue: tile 0 into buf 0
    int rb = w * 16 + jj * 8;
    async16(kb + (size_t)(rb + srow) * DK_ + lseg8, Ks[0] + rb * 64);
    async16(vb + (size_t)(rb + srow) * S_ + lseg8, Vs[0] + rb * 64);
  }
  for (int it = 0; it < nt; it++) {
    int t0 = it << 6;
    __syncthreads();  // drains tile `it` DMA; collective
    if (it + 1 < nt) {
      int t1 = t0 + 64, nb = buf ^ 1;
      for (int jj = 0; jj < 2; jj++) {
        int rb = w * 16 + jj * 8;
        async16(kb + (size_t)(t1 + rb + srow) * DK_ + lseg8, Ks[nb] + rb * 64);
        async16(vb + (size_t)(rb + srow) * S_ + t1 + lseg8, Vs[nb] + rb * 64);
      }
    }
    const ushort_t* Kb = Ks[buf];
    const ushort_t* Vb = Vs[buf];
    // S^T = K·Q^T: frag sf[f]: row = t = t0+f*16+quad*4+r, col = m = l16
    f32x4 sf[4];
    for (int f = 0; f < 4; f++) sf[f] = (f32x4){0.f, 0.f, 0.f, 0.f};
    for (int st = 0; st < 2; st++) {
      short8 kfr[4];
      for (int f = 0; f < 4; f++)
        kfr[f] = *(const short8*)(Kb + (f * 16 + l16) * 64 + (((st * 4 + quad) ^ swz) * 8));
      for (int f = 0; f < 4; f++)
        sf[f] = __builtin_amdgcn_mfma_f32_16x16x32_bf16(kfr[f], qf[st], sf[f], 0, 0, 0);
    }
    if (it == nt - 1) {  // diagonal tile: causal mask (t > s)
      int s = qs + wrow + l16;
      for (int f = 0; f < 4; f++) {
        int tb = t0 + f * 16 + quad * 4;
        for (int r = 0; r < 4; r++)
          if (tb + r > s) sf[f][r] = NEG_BIG;
      }
    }
    // fixed-scale softmax: p = exp2(s) (masked -> 0), accumulate partial l
    for (int f = 0; f < 4; f++)
      for (int r = 0; r < 4; r++) {
        float pv = exp2f(sf[f][r]);
        sf[f][r] = pv;
        l_part += pv;
      }
    // P pack: b64 writes at swizzled col4 slot (f*4+quad) ^ pm
    for (int f = 0; f < 4; f++) {
      uint2v pk;
      pk.x = pack_bf2(sf[f][0], sf[f][1]);
      pk.y = pack_bf2(sf[f][2], sf[f][3]);
      *(uint2v*)(ps + l16 * 64 + (((f * 4 + quad) ^ pm) << 2)) = pk;
    }
    asm volatile("s_waitcnt lgkmcnt(0)" ::: "memory");
    // PV: o^T += V^T(A) · P^T(B); B-frag read at swizzled col4 (st*8+quad*2)^pm
    for (int st = 0; st < 2; st++) {
      short8 vfr[4];
      for (int f = 0; f < 4; f++)
        vfr[f] = *(const short8*)(Vb + (f * 16 + l16) * 64 + (((st * 4 + quad) ^ swz) * 8));
      short8 pf = *(const short8*)(ps + l16 * 64 + (((st * 8 + quad * 2) ^ pm) << 2));
      for (int f = 0; f < 4; f++)
        o[f] = __builtin_amdgcn_mfma_f32_16x16x32_bf16(vfr[f], pf, o[f], 0, 0, 0);
    }
    buf ^= 1;
  }
  // single end-of-tile l reduction across quads, then normalized store
  float l_r = l_part;
  l_r += __shfl_xor(l_r, 16, 64);
  l_r += __shfl_xor(l_r, 32, 64);
  float inv = 1.0f / l_r;
  int s = qs + wrow + l16;
  ushort_t* op = outO + (size_t)(b * S_ + s) * D_ + h * DK_;
  for (int f = 0; f < 4; f++) {
    uint2v pk;
    pk.x = pack_bf2(o[f][0] * inv, o[f][1] * inv);
    pk.y = pack_bf2(o[f][2] * inv, o[f][3] * inv);
    *(uint2v*)(op + f * 16 + quad * 4) = pk;
  }
}

// ---------------------------------------------------------------------------
extern "C" void kernel_launch(void* const* d_in, const int* in_sizes, int n_in,
                              void* d_out, int out_size, void* d_ws, size_t ws_size,
                              hipStream_t stream) {
  const float* Q  = (const float*)d_in[0];
  const float* K  = (const float*)d_in[1];
  const float* V  = (const float*)d_in[2];
  const float* Wq = (const float*)d_in[3];
  const float* Wk = (const float*)d_in[4];
  const float* Wv = (const float*)d_in[5];
  const float* Wo = (const float*)d_in[6];
  const float* bo = (const float*)d_in[7];
  ushort_t* ws = (ushort_t*)d_ws;
  ushort_t* Wt = ws;
  ushort_t* qb = ws + ((size_t)4 << 20);
  ushort_t* kb = ws + ((size_t)8 << 20);
  ushort_t* vb = ws + ((size_t)12 << 20);
  ushort_t* qh = ws + ((size_t)16 << 20);
  ushort_t* kh = ws + ((size_t)20 << 20);
  ushort_t* vT = ws + ((size_t)24 << 20);
  ushort_t* aO = qb;

  prep<<<7168, 256, 0, stream>>>(Q, K, V, Wq, Wk, Wv, Wo, qb, kb, vb, Wt);
  qkv_proj<<<dim3(8, 32, 3), 256, 0, stream>>>(qb, kb, vb, Wt, qh, kh, vT);
  flash_attn<<<1024, 256, 0, stream>>>(qh, kh, vT, aO);
  out_proj<<<dim3(16, 32, 1), 256, 0, stream>>>(aO, Wt + ((size_t)3 << 20), bo, (float*)d_out);
}